// Round 1
// baseline (6911.342 us; speedup 1.0000x reference)
//
#include <hip/hip_runtime.h>
#include <math.h>

#define TPB 256

// 64x128 = (64 tokens) x (128 out-cols) matmul: dst(n,col) = sum_k src[n][k]*W[k*ldw+col] + bias[col]
// Thread mapping: col = tid&127, half = tid>>7 owns n = half*32 .. half*32+31.
__device__ __forceinline__ void mm64x128(const float (*src)[128],
                                         const float* __restrict__ W, int ldw, int colofs,
                                         const float* __restrict__ bias,
                                         int col, int half, float acc[32])
{
#pragma unroll
    for (int i = 0; i < 32; ++i) acc[i] = bias[colofs + col];
    for (int k = 0; k < 128; k += 4) {
        const float w0 = W[(k + 0) * ldw + colofs + col];
        const float w1 = W[(k + 1) * ldw + colofs + col];
        const float w2 = W[(k + 2) * ldw + colofs + col];
        const float w3 = W[(k + 3) * ldw + colofs + col];
#pragma unroll
        for (int i = 0; i < 32; ++i) {
            const float4 xv = *reinterpret_cast<const float4*>(&src[half * 32 + i][k]);
            acc[i] = fmaf(xv.x, w0, acc[i]);
            acc[i] = fmaf(xv.y, w1, acc[i]);
            acc[i] = fmaf(xv.z, w2, acc[i]);
            acc[i] = fmaf(xv.w, w3, acc[i]);
        }
    }
}

__global__ __launch_bounds__(TPB) void swin_attn_kernel(
    const float* __restrict__ x,
    const float* __restrict__ wq, const float* __restrict__ bq,
    const float* __restrict__ wk, const float* __restrict__ bk,
    const float* __restrict__ wv, const float* __restrict__ bv,
    const float* __restrict__ wp, const float* __restrict__ bp,
    const float* __restrict__ rpb,
    const float* __restrict__ ln1g, const float* __restrict__ ln1b,
    const float* __restrict__ gate,
    float* __restrict__ out)
{
    __shared__ float s_xn[64][128];     // xn; reused as attention-output after QKV
    __shared__ float s_q[64][128];
    __shared__ float s_kT[128][65];     // K transposed, padded
    __shared__ float s_v[64][128];
    __shared__ float s_p[64][65];       // scores/probs, padded
    __shared__ float s_rpb[15 * 15 * 8];
    __shared__ float s_mu[64], s_rs[64], s_gate[64];
    __shared__ int   s_base[64];

    const int tid = threadIdx.x;
    const int blk = blockIdx.x;
    const int b  = blk >> 10;
    const int wh = (blk >> 5) & 31;
    const int ww = blk & 31;

    for (int i = tid; i < 15 * 15 * 8; i += TPB) s_rpb[i] = rpb[i];

    // ---------- load + LN1 (shift folded into addressing) ----------
    {
        const int row = tid >> 2;     // token in window
        const int l4  = tid & 3;      // quarter of the 128 dims
        const int si = wh * 8 + (row >> 3), sj = ww * 8 + (row & 7);
        const int oi = (si + 4) & 255, oj = (sj + 4) & 255;  // original coords
        const int base = ((b * 256 + oi) * 256 + oj) * 128;
        if (l4 == 0) { s_base[row] = base; s_gate[row] = gate[oi * 256 + oj]; }
        const float* xp = x + base + l4 * 32;
        float vals[32];
        float sum = 0.f, sq = 0.f;
#pragma unroll
        for (int i = 0; i < 8; ++i) {
            const float4 v4 = reinterpret_cast<const float4*>(xp)[i];
            vals[4*i+0] = v4.x; vals[4*i+1] = v4.y; vals[4*i+2] = v4.z; vals[4*i+3] = v4.w;
            sum += v4.x + v4.y + v4.z + v4.w;
            sq  += v4.x*v4.x + v4.y*v4.y + v4.z*v4.z + v4.w*v4.w;
        }
        sum += __shfl_xor(sum, 1); sum += __shfl_xor(sum, 2);
        sq  += __shfl_xor(sq , 1); sq  += __shfl_xor(sq , 2);
        const float mu  = sum * (1.f / 128.f);
        const float var = sq * (1.f / 128.f) - mu * mu;
        const float rs  = rsqrtf(var + 1e-5f);
        if (l4 == 0) { s_mu[row] = mu; s_rs[row] = rs; }
#pragma unroll
        for (int i = 0; i < 32; ++i) {
            const int d = l4 * 32 + i;
            s_xn[row][d] = (vals[i] - mu) * rs * ln1g[d] + ln1b[d];
        }
    }
    __syncthreads();

    const int col  = tid & 127;
    const int half = tid >> 7;

    // ---------- QKV ----------
    {
        float acc[32];
        mm64x128(s_xn, wq, 128, 0, bq, col, half, acc);
#pragma unroll
        for (int i = 0; i < 32; ++i) s_q[half * 32 + i][col] = acc[i];
    }
    {
        float acc[32];
        mm64x128(s_xn, wk, 128, 0, bk, col, half, acc);
#pragma unroll
        for (int i = 0; i < 32; ++i) s_kT[col][half * 32 + i] = acc[i];
    }
    {
        float acc[32];
        mm64x128(s_xn, wv, 128, 0, bv, col, half, acc);
#pragma unroll
        for (int i = 0; i < 32; ++i) s_v[half * 32 + i][col] = acc[i];
    }
    __syncthreads();

    // ---------- attention, per head ----------
    for (int h = 0; h < 8; ++h) {
        // scores: lane m = tid&63, wave-group ng = tid>>6 owns n = ng*16..ng*16+15
        {
            const int m  = tid & 63;
            const int ng = tid >> 6;
#pragma unroll
            for (int i = 0; i < 16; ++i) {
                const int n = ng * 16 + i;
                float sc;
                if (((n >> 3) >= 4) || ((n & 7) >= 4)) {   // rmask on query row
                    sc = -1e9f;
                } else {
                    float dot = 0.f;
#pragma unroll
                    for (int j = 0; j < 16; ++j)
                        dot = fmaf(s_q[n][h * 16 + j], s_kT[h * 16 + j][m], dot);
                    // reference's scrambled bias reshape: (4096,8) -> (64,8,64)
                    // bias(n,h,m) = rpb_flat[relidx(n, jj), hsrc], jj = h*8 + (m>>3), hsrc = m&7
                    const int jj   = h * 8 + (m >> 3);
                    const int hsrc = m & 7;
                    const int dy = (n >> 3) - (jj >> 3);
                    const int dx = (n & 7) - (jj & 7);
                    const float bias = s_rpb[((dy + 7) * 15 + (dx + 7)) * 8 + hsrc];
                    sc = fmaf(dot, 0.25f, bias);
                }
                s_p[n][m] = sc;
            }
        }
        __syncthreads();
        // softmax over m, one row per thread (first 64 threads)
        if (tid < 64) {
            float mx = -1e30f;
            for (int m = 0; m < 64; ++m) mx = fmaxf(mx, s_p[tid][m]);
            float sum = 0.f;
            for (int m = 0; m < 64; ++m) {
                const float e = __expf(s_p[tid][m] - mx);
                s_p[tid][m] = e; sum += e;
            }
            const float inv = 1.f / sum;
            for (int m = 0; m < 64; ++m) s_p[tid][m] *= inv;
        }
        __syncthreads();
        // PV: d16 = tid&15, ng2 = tid>>4 owns n = ng2 + 16*i
        {
            const int d16 = tid & 15;
            const int ng2 = tid >> 4;
#pragma unroll
            for (int i = 0; i < 4; ++i) {
                const int n = ng2 + 16 * i;
                float acc = 0.f;
#pragma unroll
                for (int m = 0; m < 64; ++m)
                    acc = fmaf(s_p[n][m], s_v[m][h * 16 + d16], acc);
                s_xn[n][h * 16 + d16] = acc;   // s_xn reused as attn-out
            }
        }
        __syncthreads();
    }

    // ---------- proj + residual (+ gate*skip), write x2 ----------
    {
        float acc[32];
        mm64x128(s_xn, wp, 128, 0, bp, col, half, acc);
#pragma unroll
        for (int i = 0; i < 32; ++i) {
            const int n = half * 32 + i;
            const int base = s_base[n];
            const float xv  = x[base + col];
            const float xnv = (xv - s_mu[n]) * s_rs[n] * ln1g[col] + ln1b[col];
            const float sg  = 1.f / (1.f + __expf(-s_gate[n]));
            out[base + col] = xnv + acc[i] + sg * xv;
        }
    }
}

__global__ __launch_bounds__(TPB) void swin_mlp_kernel(
    const float* __restrict__ ln2g, const float* __restrict__ ln2b,
    const float* __restrict__ w1, const float* __restrict__ b1,
    const float* __restrict__ w2, const float* __restrict__ b2,
    float* __restrict__ io)
{
    __shared__ float s_xn[64][128];
    __shared__ float s_h[64][128];
    const int tid  = threadIdx.x;
    const int base = blockIdx.x * (64 * 128);

    // ---------- LN2 ----------
    {
        const int row = tid >> 2;
        const int l4  = tid & 3;
        const float* xp = io + base + row * 128 + l4 * 32;
        float vals[32];
        float sum = 0.f, sq = 0.f;
#pragma unroll
        for (int i = 0; i < 8; ++i) {
            const float4 v4 = reinterpret_cast<const float4*>(xp)[i];
            vals[4*i+0] = v4.x; vals[4*i+1] = v4.y; vals[4*i+2] = v4.z; vals[4*i+3] = v4.w;
            sum += v4.x + v4.y + v4.z + v4.w;
            sq  += v4.x*v4.x + v4.y*v4.y + v4.z*v4.z + v4.w*v4.w;
        }
        sum += __shfl_xor(sum, 1); sum += __shfl_xor(sum, 2);
        sq  += __shfl_xor(sq , 1); sq  += __shfl_xor(sq , 2);
        const float mu  = sum * (1.f / 128.f);
        const float var = sq * (1.f / 128.f) - mu * mu;
        const float rs  = rsqrtf(var + 1e-5f);
#pragma unroll
        for (int i = 0; i < 32; ++i) {
            const int d = l4 * 32 + i;
            s_xn[row][d] = (vals[i] - mu) * rs * ln2g[d] + ln2b[d];
        }
    }
    __syncthreads();

    const int col  = tid & 127;
    const int half = tid >> 7;
    float acc[32];
#pragma unroll
    for (int i = 0; i < 32; ++i) acc[i] = b2[col];

    for (int cc = 0; cc < 4; ++cc) {
        // h-chunk = gelu(xn @ w1[:, cc*128 : cc*128+128] + b1[...])
        float hacc[32];
        mm64x128(s_xn, w1, 512, cc * 128, b1, col, half, hacc);
        __syncthreads();   // previous chunk's s_h consumers done
#pragma unroll
        for (int i = 0; i < 32; ++i) {
            const float v = hacc[i];
            s_h[half * 32 + i][col] = 0.5f * v * (1.f + erff(v * 0.70710678118654752f));
        }
        __syncthreads();
        // y += h_chunk @ w2[cc*128 : cc*128+128, :]
        for (int k = 0; k < 128; k += 4) {
            const float u0 = w2[(cc * 128 + k + 0) * 128 + col];
            const float u1 = w2[(cc * 128 + k + 1) * 128 + col];
            const float u2 = w2[(cc * 128 + k + 2) * 128 + col];
            const float u3 = w2[(cc * 128 + k + 3) * 128 + col];
#pragma unroll
            for (int i = 0; i < 32; ++i) {
                const float4 hv = *reinterpret_cast<const float4*>(&s_h[half * 32 + i][k]);
                acc[i] = fmaf(hv.x, u0, acc[i]);
                acc[i] = fmaf(hv.y, u1, acc[i]);
                acc[i] = fmaf(hv.z, u2, acc[i]);
                acc[i] = fmaf(hv.w, u3, acc[i]);
            }
        }
    }
    // residual + in-place write (each element read/written by the same thread only)
#pragma unroll
    for (int i = 0; i < 32; ++i) {
        const int idx = base + (half * 32 + i) * 128 + col;
        io[idx] = io[idx] + acc[i];
    }
}

extern "C" void kernel_launch(void* const* d_in, const int* in_sizes, int n_in,
                              void* d_out, int out_size, void* d_ws, size_t ws_size,
                              hipStream_t stream) {
    (void)in_sizes; (void)n_in; (void)d_ws; (void)ws_size; (void)out_size;
    const float* x    = (const float*)d_in[0];
    const float* wq   = (const float*)d_in[1];
    const float* bq   = (const float*)d_in[2];
    const float* wk   = (const float*)d_in[3];
    const float* bk   = (const float*)d_in[4];
    const float* wv   = (const float*)d_in[5];
    const float* bv   = (const float*)d_in[6];
    const float* wp   = (const float*)d_in[7];
    const float* bp   = (const float*)d_in[8];
    const float* rpb  = (const float*)d_in[9];
    const float* ln1g = (const float*)d_in[10];
    const float* ln1b = (const float*)d_in[11];
    const float* ln2g = (const float*)d_in[12];
    const float* ln2b = (const float*)d_in[13];
    const float* w1   = (const float*)d_in[14];
    const float* b1   = (const float*)d_in[15];
    const float* w2   = (const float*)d_in[16];
    const float* b2   = (const float*)d_in[17];
    const float* gate = (const float*)d_in[18];
    float* out = (float*)d_out;

    swin_attn_kernel<<<8192, TPB, 0, stream>>>(x, wq, bq, wk, bk, wv, bv, wp, bp,
                                               rpb, ln1g, ln1b, gate, out);
    swin_mlp_kernel<<<8192, TPB, 0, stream>>>(ln2g, ln2b, w1, b1, w2, b2, out);
}

// Round 2
// 992.444 us; speedup vs baseline: 6.9640x; 6.9640x over previous
//
#include <hip/hip_runtime.h>
#include <hip/hip_bf16.h>
#include <math.h>

#define TPB 256

typedef __attribute__((ext_vector_type(8))) __bf16 bf16x8;
typedef __attribute__((ext_vector_type(4))) float f32x4;

// ---- swizzled LDS helpers: byte = row*rowBytes + (byteOff ^ ((row&7)<<4)) ----
static __device__ __forceinline__ bf16x8 lds_frag(const char* base, int row, int byteOff, int rowBytes) {
    return *reinterpret_cast<const bf16x8*>(base + row * rowBytes + (byteOff ^ ((row & 7) << 4)));
}
static __device__ __forceinline__ void lds_wr_bf16(char* base, int row, int col, int rowBytes, float v) {
    *reinterpret_cast<__bf16*>(base + row * rowBytes + ((col << 1) ^ ((row & 7) << 4))) = (__bf16)v;
}

// C[64][128] = A(lds,swz) @ WT^T + bias. Wave w owns col-tiles {w, w+4}, all 4 row-tiles.
// acc[ct2][rt]; C elem: row = rt*16 + (lane>>4)*4 + r, col = (w+ct2*4)*16 + (lane&15)
static __device__ __forceinline__ void gemm_64x128(
    const char* sA, const __bf16* __restrict__ WT, const float* __restrict__ bias,
    int w, int lane, f32x4 acc[2][4])
{
    const int ar = lane & 15, kg = lane >> 4;
    bf16x8 a[4][4];
#pragma unroll
    for (int rt = 0; rt < 4; ++rt)
#pragma unroll
        for (int kc = 0; kc < 4; ++kc)
            a[rt][kc] = lds_frag(sA, rt * 16 + ar, kc * 64 + (kg << 4), 256);
#pragma unroll
    for (int ct2 = 0; ct2 < 2; ++ct2) {
        const int ct = w + ct2 * 4;
        const int brow = ct * 16 + ar;
        bf16x8 b[4];
#pragma unroll
        for (int kc = 0; kc < 4; ++kc)
            b[kc] = *reinterpret_cast<const bf16x8*>(WT + brow * 128 + kc * 32 + (kg << 3));
        const float bb = bias[brow];
#pragma unroll
        for (int rt = 0; rt < 4; ++rt) {
            f32x4 c = {bb, bb, bb, bb};
#pragma unroll
            for (int kc = 0; kc < 4; ++kc)
                c = __builtin_amdgcn_mfma_f32_16x16x32_bf16(a[rt][kc], b[kc], c, 0, 0, 0);
            acc[ct2][rt] = c;
        }
    }
}

// ---- weight convert+transpose to bf16 in ws ----
// layout (elements): wqT 0, wkT 16384, wvT 32768, wpT 49152, w1T 65536 ([512][128]), w2T 131072 ([128][512])
__global__ void convert_w(const float* __restrict__ wq, const float* __restrict__ wk,
                          const float* __restrict__ wv, const float* __restrict__ wp,
                          const float* __restrict__ w1, const float* __restrict__ w2,
                          __bf16* __restrict__ ws)
{
    int g = blockIdx.x * 256 + threadIdx.x;
    if (g < 65536) {
        int which = g >> 14, idx = g & 16383, n = idx >> 7, k = idx & 127;
        const float* W = (which == 0) ? wq : (which == 1) ? wk : (which == 2) ? wv : wp;
        ws[g] = (__bf16)W[k * 128 + n];
    } else if (g < 131072) {
        int idx = g - 65536, n = idx >> 7, k = idx & 127;
        ws[g] = (__bf16)w1[k * 512 + n];
    } else if (g < 196608) {
        int idx = g - 131072, n = idx >> 9, k = idx & 511;
        ws[g] = (__bf16)w2[k * 128 + n];
    }
}

__global__ __launch_bounds__(TPB, 2) void swin_attn_kernel(
    const float* __restrict__ x,
    const __bf16* __restrict__ wqT, const float* __restrict__ bq,
    const __bf16* __restrict__ wkT, const float* __restrict__ bk,
    const __bf16* __restrict__ wvT, const float* __restrict__ bv,
    const __bf16* __restrict__ wpT, const float* __restrict__ bp,
    const float* __restrict__ rpb,
    const float* __restrict__ ln1g, const float* __restrict__ ln1b,
    const float* __restrict__ gate,
    float* __restrict__ out)
{
    __shared__ __align__(16) char s_xn[64 * 256];   // bf16 [64][128] swz; later attn-out
    __shared__ __align__(16) char s_q [64 * 256];   // bf16 [64][128] swz
    __shared__ __align__(16) char s_k [64 * 256];   // bf16 [64][128] swz
    __shared__ __align__(16) char s_vT[128 * 128];  // bf16 [128][64] swz (row = dim)
    __shared__ __align__(16) char s_p [64 * 128];   // bf16 [64][64] swz
    __shared__ __bf16 s_rpb[15 * 15 * 8];
    __shared__ float s_mu[64], s_rs[64], s_gate[64];
    __shared__ int   s_base[64];

    const int tid = threadIdx.x;
    const int blk = blockIdx.x;
    const int b  = blk >> 10;
    const int wh = (blk >> 5) & 31;
    const int ww = blk & 31;

    for (int i = tid; i < 15 * 15 * 8; i += TPB) s_rpb[i] = (__bf16)rpb[i];

    // ---------- load + LN1 (shift folded into addressing), write bf16 swizzled ----------
    {
        const int row = tid >> 2;
        const int l4  = tid & 3;
        const int si = wh * 8 + (row >> 3), sj = ww * 8 + (row & 7);
        const int oi = (si + 4) & 255, oj = (sj + 4) & 255;
        const int base = ((b * 256 + oi) * 256 + oj) * 128;
        if (l4 == 0) { s_base[row] = base; s_gate[row] = gate[oi * 256 + oj]; }
        const float* xp = x + base + l4 * 32;
        float vals[32];
        float sum = 0.f, sq = 0.f;
#pragma unroll
        for (int i = 0; i < 8; ++i) {
            const float4 v4 = reinterpret_cast<const float4*>(xp)[i];
            vals[4*i+0] = v4.x; vals[4*i+1] = v4.y; vals[4*i+2] = v4.z; vals[4*i+3] = v4.w;
            sum += v4.x + v4.y + v4.z + v4.w;
            sq  += v4.x*v4.x + v4.y*v4.y + v4.z*v4.z + v4.w*v4.w;
        }
        sum += __shfl_xor(sum, 1); sum += __shfl_xor(sum, 2);
        sq  += __shfl_xor(sq , 1); sq  += __shfl_xor(sq , 2);
        const float mu  = sum * (1.f / 128.f);
        const float var = sq * (1.f / 128.f) - mu * mu;
        const float rs  = rsqrtf(var + 1e-5f);
        if (l4 == 0) { s_mu[row] = mu; s_rs[row] = rs; }
#pragma unroll
        for (int j = 0; j < 4; ++j) {
            bf16x8 pk;
#pragma unroll
            for (int e = 0; e < 8; ++e) {
                const int d = l4 * 32 + j * 8 + e;
                pk[e] = (__bf16)((vals[j*8+e] - mu) * rs * ln1g[d] + ln1b[d]);
            }
            const int byteOff = (l4 * 64 + j * 16) ^ ((row & 7) << 4);
            *reinterpret_cast<bf16x8*>(s_xn + row * 256 + byteOff) = pk;
        }
    }
    __syncthreads();

    const int lane = tid & 63, w = tid >> 6;
    const int ar = lane & 15, kg = lane >> 4;

    // ---------- QKV via MFMA ----------
    {
        f32x4 acc[2][4];
        gemm_64x128(s_xn, wqT, bq, w, lane, acc);
#pragma unroll
        for (int ct2 = 0; ct2 < 2; ++ct2)
#pragma unroll
            for (int rt = 0; rt < 4; ++rt)
#pragma unroll
                for (int r = 0; r < 4; ++r)
                    lds_wr_bf16(s_q, rt*16 + kg*4 + r, (w + ct2*4)*16 + ar, 256, acc[ct2][rt][r]);
        gemm_64x128(s_xn, wkT, bk, w, lane, acc);
#pragma unroll
        for (int ct2 = 0; ct2 < 2; ++ct2)
#pragma unroll
            for (int rt = 0; rt < 4; ++rt)
#pragma unroll
                for (int r = 0; r < 4; ++r)
                    lds_wr_bf16(s_k, rt*16 + kg*4 + r, (w + ct2*4)*16 + ar, 256, acc[ct2][rt][r]);
        gemm_64x128(s_xn, wvT, bv, w, lane, acc);
#pragma unroll
        for (int ct2 = 0; ct2 < 2; ++ct2)
#pragma unroll
            for (int rt = 0; rt < 4; ++rt)
#pragma unroll
                for (int r = 0; r < 4; ++r)   // transposed: s_vT[dim][token]
                    lds_wr_bf16(s_vT, (w + ct2*4)*16 + ar, rt*16 + kg*4 + r, 128, acc[ct2][rt][r]);
    }
    __syncthreads();

    // ---------- per-head attention (no barriers: each wave owns rows w*16..w*16+15) ----------
    for (int h = 0; h < 8; ++h) {
        // scores: A = Q rows (K=16, zero-padded to 32), B = K rows as K^T
        bf16x8 aq = {};
        if (lane < 32) aq = lds_frag(s_q, w * 16 + ar, h * 32 + (kg << 4), 256);
        f32x4 sc[4];
#pragma unroll
        for (int ct = 0; ct < 4; ++ct) {
            bf16x8 bk8 = {};
            if (lane < 32) bk8 = lds_frag(s_k, ct * 16 + ar, h * 32 + (kg << 4), 256);
            f32x4 z = {0.f, 0.f, 0.f, 0.f};
            sc[ct] = __builtin_amdgcn_mfma_f32_16x16x32_bf16(aq, bk8, z, 0, 0, 0);
        }
        // bias + mask + softmax (rows local to 16-lane groups)
#pragma unroll
        for (int r = 0; r < 4; ++r) {
            const int n = w * 16 + kg * 4 + r;
            const bool masked = ((n >> 3) >= 4) || ((n & 7) >= 4);
#pragma unroll
            for (int ct = 0; ct < 4; ++ct) {
                const int m = ct * 16 + ar;
                if (masked) { sc[ct][r] = -1e9f; }
                else {
                    const int dy = (n >> 3) - h;
                    const int dx = (n & 7) - (m >> 3);
                    const float bias = (float)s_rpb[((dy + 7) * 15 + (dx + 7)) * 8 + (m & 7)];
                    sc[ct][r] = sc[ct][r] * 0.25f + bias;
                }
            }
            float mx = fmaxf(fmaxf(sc[0][r], sc[1][r]), fmaxf(sc[2][r], sc[3][r]));
            mx = fmaxf(mx, __shfl_xor(mx, 1)); mx = fmaxf(mx, __shfl_xor(mx, 2));
            mx = fmaxf(mx, __shfl_xor(mx, 4)); mx = fmaxf(mx, __shfl_xor(mx, 8));
            float sm = 0.f;
#pragma unroll
            for (int ct = 0; ct < 4; ++ct) {
                const float e = __expf(sc[ct][r] - mx);
                sc[ct][r] = e; sm += e;
            }
            sm += __shfl_xor(sm, 1); sm += __shfl_xor(sm, 2);
            sm += __shfl_xor(sm, 4); sm += __shfl_xor(sm, 8);
            const float inv = 1.f / sm;
#pragma unroll
            for (int ct = 0; ct < 4; ++ct)
                lds_wr_bf16(s_p, n, ct * 16 + ar, 128, sc[ct][r] * inv);
        }
        // PV: A = P rows (own), B = V^T rows h*16..h*16+15
        f32x4 o = {0.f, 0.f, 0.f, 0.f};
#pragma unroll
        for (int kc = 0; kc < 2; ++kc) {
            bf16x8 ap = lds_frag(s_p,  w * 16 + ar, kc * 64 + (kg << 4), 128);
            bf16x8 bv8 = lds_frag(s_vT, h * 16 + ar, kc * 64 + (kg << 4), 128);
            o = __builtin_amdgcn_mfma_f32_16x16x32_bf16(ap, bv8, o, 0, 0, 0);
        }
#pragma unroll
        for (int r = 0; r < 4; ++r)   // attn-out into s_xn (xn no longer needed)
            lds_wr_bf16(s_xn, w * 16 + kg * 4 + r, h * 16 + ar, 256, o[r]);
    }
    __syncthreads();

    // ---------- proj + residual (+ gate*skip) ----------
    {
        f32x4 acc[2][4];
        gemm_64x128(s_xn, wpT, bp, w, lane, acc);
#pragma unroll
        for (int ct2 = 0; ct2 < 2; ++ct2)
#pragma unroll
            for (int rt = 0; rt < 4; ++rt)
#pragma unroll
                for (int r = 0; r < 4; ++r) {
                    const int n = rt * 16 + kg * 4 + r;
                    const int col = (w + ct2 * 4) * 16 + ar;
                    const int base = s_base[n];
                    const float xv  = x[base + col];
                    const float xnv = (xv - s_mu[n]) * s_rs[n] * ln1g[col] + ln1b[col];
                    const float sg  = 1.f / (1.f + __expf(-s_gate[n]));
                    out[base + col] = xnv + acc[ct2][rt][r] + sg * xv;
                }
    }
}

__global__ __launch_bounds__(TPB, 2) void swin_mlp_kernel(
    const float* __restrict__ ln2g, const float* __restrict__ ln2b,
    const __bf16* __restrict__ w1T, const float* __restrict__ b1,
    const __bf16* __restrict__ w2T, const float* __restrict__ b2,
    float* __restrict__ io)
{
    __shared__ __align__(16) char s_buf[64 * 1024];  // phase1: xn bf16 [64][128] swz; phase2: h bf16 [64][512] swz
    const int tid  = threadIdx.x;
    const int base = blockIdx.x * (64 * 128);
    const int lane = tid & 63, w = tid >> 6;
    const int ar = lane & 15, kg = lane >> 4;

    // ---------- LN2 -> s_buf (as [64][256B] rows) ----------
    {
        const int row = tid >> 2;
        const int l4  = tid & 3;
        const float* xp = io + base + row * 128 + l4 * 32;
        float vals[32];
        float sum = 0.f, sq = 0.f;
#pragma unroll
        for (int i = 0; i < 8; ++i) {
            const float4 v4 = reinterpret_cast<const float4*>(xp)[i];
            vals[4*i+0] = v4.x; vals[4*i+1] = v4.y; vals[4*i+2] = v4.z; vals[4*i+3] = v4.w;
            sum += v4.x + v4.y + v4.z + v4.w;
            sq  += v4.x*v4.x + v4.y*v4.y + v4.z*v4.z + v4.w*v4.w;
        }
        sum += __shfl_xor(sum, 1); sum += __shfl_xor(sum, 2);
        sq  += __shfl_xor(sq , 1); sq  += __shfl_xor(sq , 2);
        const float mu  = sum * (1.f / 128.f);
        const float var = sq * (1.f / 128.f) - mu * mu;
        const float rs  = rsqrtf(var + 1e-5f);
#pragma unroll
        for (int j = 0; j < 4; ++j) {
            bf16x8 pk;
#pragma unroll
            for (int e = 0; e < 8; ++e) {
                const int d = l4 * 32 + j * 8 + e;
                pk[e] = (__bf16)((vals[j*8+e] - mu) * rs * ln2g[d] + ln2b[d]);
            }
            const int byteOff = (l4 * 64 + j * 16) ^ ((row & 7) << 4);
            *reinterpret_cast<bf16x8*>(s_buf + row * 256 + byteOff) = pk;
        }
    }
    __syncthreads();

    // hoist A-frags (xn) to registers, then s_buf is reused for h
    bf16x8 a[4][4];
#pragma unroll
    for (int rt = 0; rt < 4; ++rt)
#pragma unroll
        for (int kc = 0; kc < 4; ++kc)
            a[rt][kc] = lds_frag(s_buf, rt * 16 + ar, kc * 64 + (kg << 4), 256);
    __syncthreads();

    // ---------- GEMM1: h = gelu(xn @ w1 + b1), h -> s_buf as [64][1024B] swz rows ----------
    for (int ct_i = 0; ct_i < 8; ++ct_i) {
        const int ct = w + 4 * ct_i;
        const int brow = ct * 16 + ar;
        bf16x8 bfr[4];
#pragma unroll
        for (int kc = 0; kc < 4; ++kc)
            bfr[kc] = *reinterpret_cast<const bf16x8*>(w1T + brow * 128 + kc * 32 + (kg << 3));
        const float bb = b1[brow];
#pragma unroll
        for (int rt = 0; rt < 4; ++rt) {
            f32x4 c = {bb, bb, bb, bb};
#pragma unroll
            for (int kc = 0; kc < 4; ++kc)
                c = __builtin_amdgcn_mfma_f32_16x16x32_bf16(a[rt][kc], bfr[kc], c, 0, 0, 0);
#pragma unroll
            for (int r = 0; r < 4; ++r) {
                const float v = c[r];
                // tanh-form GELU (err ~1e-3 abs, fine vs 0.158 threshold)
                const float t = 0.7978845608028654f * (v + 0.044715f * v * v * v);
                const float th = 1.f - 2.f / (__expf(2.f * t) + 1.f);
                lds_wr_bf16(s_buf, rt * 16 + kg * 4 + r, brow, 1024, 0.5f * v * (1.f + th));
            }
        }
    }
    __syncthreads();

    // ---------- GEMM2: y = h @ w2 + b2 ----------
    f32x4 acc2[2][4];
#pragma unroll
    for (int ct2 = 0; ct2 < 2; ++ct2) {
        const float bb = b2[(w + ct2 * 4) * 16 + ar];
#pragma unroll
        for (int rt = 0; rt < 4; ++rt) acc2[ct2][rt] = {bb, bb, bb, bb};
    }
    for (int kc = 0; kc < 16; ++kc) {
        bf16x8 ah[4];
#pragma unroll
        for (int rt = 0; rt < 4; ++rt)
            ah[rt] = lds_frag(s_buf, rt * 16 + ar, kc * 64 + (kg << 4), 1024);
#pragma unroll
        for (int ct2 = 0; ct2 < 2; ++ct2) {
            const int brow = (w + ct2 * 4) * 16 + ar;
            const bf16x8 bw = *reinterpret_cast<const bf16x8*>(w2T + brow * 512 + kc * 32 + (kg << 3));
#pragma unroll
            for (int rt = 0; rt < 4; ++rt)
                acc2[ct2][rt] = __builtin_amdgcn_mfma_f32_16x16x32_bf16(ah[rt], bw, acc2[ct2][rt], 0, 0, 0);
        }
    }
    // residual, in-place
#pragma unroll
    for (int ct2 = 0; ct2 < 2; ++ct2)
#pragma unroll
        for (int rt = 0; rt < 4; ++rt)
#pragma unroll
            for (int r = 0; r < 4; ++r) {
                const int n = rt * 16 + kg * 4 + r;
                const int col = (w + ct2 * 4) * 16 + ar;
                const int idx = base + n * 128 + col;
                io[idx] = io[idx] + acc2[ct2][rt][r];
            }
}

extern "C" void kernel_launch(void* const* d_in, const int* in_sizes, int n_in,
                              void* d_out, int out_size, void* d_ws, size_t ws_size,
                              hipStream_t stream) {
    (void)in_sizes; (void)n_in; (void)ws_size; (void)out_size;
    const float* x    = (const float*)d_in[0];
    const float* wq   = (const float*)d_in[1];
    const float* bq   = (const float*)d_in[2];
    const float* wk   = (const float*)d_in[3];
    const float* bk   = (const float*)d_in[4];
    const float* wv   = (const float*)d_in[5];
    const float* bv   = (const float*)d_in[6];
    const float* wp   = (const float*)d_in[7];
    const float* bp   = (const float*)d_in[8];
    const float* rpb  = (const float*)d_in[9];
    const float* ln1g = (const float*)d_in[10];
    const float* ln1b = (const float*)d_in[11];
    const float* ln2g = (const float*)d_in[12];
    const float* ln2b = (const float*)d_in[13];
    const float* w1   = (const float*)d_in[14];
    const float* b1   = (const float*)d_in[15];
    const float* w2   = (const float*)d_in[16];
    const float* b2   = (const float*)d_in[17];
    const float* gate = (const float*)d_in[18];
    float* out = (float*)d_out;

    __bf16* ws = (__bf16*)d_ws;
    const __bf16* wqT = ws;
    const __bf16* wkT = ws + 16384;
    const __bf16* wvT = ws + 32768;
    const __bf16* wpT = ws + 49152;
    const __bf16* w1T = ws + 65536;
    const __bf16* w2T = ws + 131072;

    convert_w<<<768, 256, 0, stream>>>(wq, wk, wv, wp, w1, w2, ws);
    swin_attn_kernel<<<8192, TPB, 0, stream>>>(x, wqT, bq, wkT, bk, wvT, bv, wpT, bp,
                                               rpb, ln1g, ln1b, gate, out);
    swin_mlp_kernel<<<8192, TPB, 0, stream>>>(ln2g, ln2b, w1T, b1, w2T, b2, out);
}